// Round 7
// baseline (530.546 us; speedup 1.0000x reference)
//
#include <hip/hip_runtime.h>

// Problem constants (fixed by reference setup_inputs)
#define BB   2048   // batch
#define LL   20     // seq length
#define JJ   25     // joints
#define CC   256    // channels
#define FF   64     // filters
#define KK   4      // hops
#define IPAD 32     // padded i-extent of Mt rows (128B-aligned for s_load)
#define MTSZ (JJ * IPAD)   // 800 floats per l-slice of Mt

typedef float f4 __attribute__((ext_vector_type(4)));

// ---------------------------------------------------------------------------
// Kernel 1 (tiny): Mt[l,j,i] = M[l,i,j] = sum_k w[k,l]*A[i,j]^k  (TRANSPOSED
// so the hot kernel reads a contiguous i-column per j via the scalar pipe).
// w[k,l] = sum_n kern[n,k,l]. One block per l; pad i>=JJ zeroed.
// ---------------------------------------------------------------------------
__global__ __launch_bounds__(256) void GCN_precompute_Mt(
    const float* __restrict__ A,     // [J,J]
    const float* __restrict__ kern,  // [F,K,L]
    float* __restrict__ Mt)          // [LL][JJ][IPAD]
{
    const int l = blockIdx.x;
    __shared__ float w_sh[KK];

    {
        const int k    = threadIdx.x >> 6;   // wave id == hop (KK==4 waves)
        const int lane = threadIdx.x & 63;   // filter index (FF==64 exactly)
        float v = kern[lane * (KK * LL) + k * LL + l];
        v += __shfl_xor(v, 32, 64);
        v += __shfl_xor(v, 16, 64);
        v += __shfl_xor(v, 8, 64);
        v += __shfl_xor(v, 4, 64);
        v += __shfl_xor(v, 2, 64);
        v += __shfl_xor(v, 1, 64);
        if (lane == 0) w_sh[k] = v;
    }
    __syncthreads();

    const float w0 = w_sh[0], w1 = w_sh[1], w2 = w_sh[2], w3 = w_sh[3];

    for (int e = threadIdx.x; e < MTSZ; e += 256) {
        const int j = e / IPAD;          // 0..24
        const int i = e - j * IPAD;      // 0..31 (pad i>=25 -> 0)
        float m = 0.0f;
        if (i < JJ) {
            const float a = A[i * JJ + j];
            m = w0 + a * (w1 + a * (w2 + a * w3));   // Horner; a=0 -> w0 (0^0==1)
        }
        Mt[l * MTSZ + e] = m;
    }
}

// ---------------------------------------------------------------------------
// Kernel 2 (hot): f4 (16B/lane = 1KB/wave) transactions on BOTH streams.
// acc[25] (f4, 100 VGPR) held in registers; x streamed one j at a time so
// only ~4-5 loads are in flight (fits 128-VGPR / 4 waves/SIMD). M comes in
// via the scalar pipe (uniform s_load of Mt column j) -> no LDS, no barriers.
// Grid: LL*(BB/4); block = 256 threads = 4 batch-subs x 64 f4 cols.
// ---------------------------------------------------------------------------
__global__ __launch_bounds__(256, 4) void GCNLayer_72602127172024_kernel(
    const float* __restrict__ x,     // [B,L,J,C]
    const float* __restrict__ Mt,    // [LL][JJ][IPAD]
    float* __restrict__ out)         // [L,B,J,C]
{
    const int tid = threadIdx.x;
    const int gid = blockIdx.x;
    const int l   = gid >> 9;           // / (BB/4) == /512
    const int bb  = (gid & 511) << 2;   // base batch of this block

    const int bsub = tid >> 6;        // 0..3
    const int c4   = tid & 63;        // f4 column (CC/4 == 64)
    const int b    = bb + bsub;

    const f4* __restrict__ xin =
        reinterpret_cast<const f4*>(x) + ((b * LL + l) * JJ) * 64 + c4;
    f4* __restrict__ oout =
        reinterpret_cast<f4*>(out) + ((l * BB + b) * JJ) * 64 + c4;

    const float* __restrict__ Mtl = Mt + l * MTSZ;   // uniform (SGPR) base

    f4 acc[JJ];
#pragma unroll
    for (int i = 0; i < JJ; ++i) acc[i] = (f4){0.0f, 0.0f, 0.0f, 0.0f};

    // Stream x: one 1KB wave-load per j, each feeding 100 fmac against the
    // scalar-pipe M column. Compiler pipelines ~4-5 loads ahead.
#pragma unroll
    for (int j = 0; j < JJ; ++j) {
        const f4 xj = __builtin_nontemporal_load(xin + j * 64);
        const float* __restrict__ mcol = Mtl + j * IPAD;
#pragma unroll
        for (int i = 0; i < JJ; ++i) {
            const float m = mcol[i];           // uniform -> s_load (K$-hot)
            acc[i].x = fmaf(m, xj.x, acc[i].x);
            acc[i].y = fmaf(m, xj.y, acc[i].y);
            acc[i].z = fmaf(m, xj.z, acc[i].z);
            acc[i].w = fmaf(m, xj.w, acc[i].w);
        }
    }

#pragma unroll
    for (int i = 0; i < JJ; ++i)
        __builtin_nontemporal_store(acc[i], oout + i * 64);
}

extern "C" void kernel_launch(void* const* d_in, const int* in_sizes, int n_in,
                              void* d_out, int out_size, void* d_ws, size_t ws_size,
                              hipStream_t stream) {
    const float* x    = (const float*)d_in[0];   // [B,L,J,C]
    const float* A    = (const float*)d_in[1];   // [J,J]
    const float* kern = (const float*)d_in[2];   // [F,K,L]
    float* out        = (float*)d_out;           // [L,B,J,C]
    float* Mt         = (float*)d_ws;            // [LL][JJ][IPAD] = 64 KB

    GCN_precompute_Mt<<<LL, 256, 0, stream>>>(A, kern, Mt);

    const int grid = LL * (BB / 4);  // 10240 blocks
    GCNLayer_72602127172024_kernel<<<grid, 256, 0, stream>>>(x, Mt, out);
}

// Round 8
// 407.776 us; speedup vs baseline: 1.3011x; 1.3011x over previous
//
#include <hip/hip_runtime.h>

// Problem constants (fixed by reference setup_inputs)
#define BB   2048   // batch
#define LL   20     // seq length
#define JJ   25     // joints
#define CC   256    // channels
#define FF   64     // filters
#define KK   4      // hops
#define JPAD 28     // padded row length (rows 16B-aligned for s_load_dwordx4)
#define MSZ  (JJ * JPAD)   // 700 floats per l-slice of M

typedef float f2 __attribute__((ext_vector_type(2)));
typedef float f4 __attribute__((ext_vector_type(4)));

// ---------------------------------------------------------------------------
// Kernel 1 (tiny): M[l,i,j] = sum_k w[k,l]*A[i,j]^k, w[k,l]=sum_n kern[n,k,l]
// One block per l; writes [LL][JJ][JPAD] floats (pad zeroed) into d_ws.
// ---------------------------------------------------------------------------
__global__ __launch_bounds__(256) void GCN_precompute_M(
    const float* __restrict__ A,     // [J,J]
    const float* __restrict__ kern,  // [F,K,L]
    float* __restrict__ Mg)          // [LL][JJ][JPAD]
{
    const int l = blockIdx.x;
    __shared__ float w_sh[KK];

    {
        const int k    = threadIdx.x >> 6;   // wave id == hop (KK==4 waves)
        const int lane = threadIdx.x & 63;   // filter index (FF==64 exactly)
        float v = kern[lane * (KK * LL) + k * LL + l];
        v += __shfl_xor(v, 32, 64);
        v += __shfl_xor(v, 16, 64);
        v += __shfl_xor(v, 8, 64);
        v += __shfl_xor(v, 4, 64);
        v += __shfl_xor(v, 2, 64);
        v += __shfl_xor(v, 1, 64);
        if (lane == 0) w_sh[k] = v;
    }
    __syncthreads();

    const float w0 = w_sh[0], w1 = w_sh[1], w2 = w_sh[2], w3 = w_sh[3];

    for (int e = threadIdx.x; e < MSZ; e += 256) {
        const int i = e / JPAD;
        const int j = e - i * JPAD;
        float m = 0.0f;
        if (j < JJ) {
            const float a = A[i * JJ + j];
            m = w0 + a * (w1 + a * (w2 + a * w3));   // Horner; a=0 -> w0 (0^0==1)
        }
        Mg[l * MSZ + e] = m;
    }
}

// ---------------------------------------------------------------------------
// Kernel 2 (hot): TWO slab-pairs per block, both 25-deep nt load bursts issued
// back-to-back up front (50 independent loads = 25.6KB in flight per wave),
// then compute+store A, compute+store B. M via the scalar pipe (uniform
// s_load, K$-hot) -> no LDS, no barriers, nothing re-syncs the waves.
// Straight-line, all indices compile-time (no r3 spill mode).
// Grid: LL*(BB/4); block = 256 threads = 2 batch-subs x 128 f2 cols.
// ---------------------------------------------------------------------------
__global__ __launch_bounds__(256, 4) void GCNLayer_72602127172024_kernel(
    const float* __restrict__ x,     // [B,L,J,C]
    const float* __restrict__ Mg,    // [LL][JJ][JPAD]
    float* __restrict__ out)         // [L,B,J,C]
{
    const int tid = threadIdx.x;
    const int gid = blockIdx.x;
    const int l   = gid >> 9;           // / (BB/4) == /512
    const int bb  = (gid & 511) << 2;   // base batch: this block owns bb..bb+3

    const int bsub = tid >> 7;        // 0..1
    const int c2   = tid & 127;       // float2 column (CC/2 == 128)
    const int bA   = bb + bsub;       // slab-pair A: batches bb, bb+1
    const int bB   = bb + 2 + bsub;   // slab-pair B: batches bb+2, bb+3

    const f2* __restrict__ xinA =
        reinterpret_cast<const f2*>(x) + ((bA * LL + l) * JJ) * 128 + c2;
    const f2* __restrict__ xinB =
        reinterpret_cast<const f2*>(x) + ((bB * LL + l) * JJ) * 128 + c2;
    f2* __restrict__ ooutA =
        reinterpret_cast<f2*>(out) + ((l * BB + bA) * JJ) * 128 + c2;
    f2* __restrict__ ooutB =
        reinterpret_cast<f2*>(out) + ((l * BB + bB) * JJ) * 128 + c2;

    // ---- both load bursts, back-to-back: 50 independent nt loads ----
    f2 xvA[JJ], xvB[JJ];
#pragma unroll
    for (int j = 0; j < JJ; ++j)
        xvA[j] = __builtin_nontemporal_load(xinA + j * 128);
#pragma unroll
    for (int j = 0; j < JJ; ++j)
        xvB[j] = __builtin_nontemporal_load(xinB + j * 128);

    // Uniform M base for this block's l (SGPR address); same M for A and B.
    const float* __restrict__ Msl = Mg + l * MSZ;

    // ---- compute + store A (B's loads still landing underneath) ----
#pragma unroll 2
    for (int i = 0; i < JJ; ++i) {
        const float* __restrict__ mrow = Msl + i * JPAD;
        f2 acc = {0.0f, 0.0f};
#pragma unroll
        for (int j = 0; j < JJ; ++j) {
            const float m = mrow[j];          // uniform -> scalar load
            acc.x = fmaf(m, xvA[j].x, acc.x);
            acc.y = fmaf(m, xvA[j].y, acc.y);
        }
        __builtin_nontemporal_store(acc, ooutA + i * 128);
    }

    // ---- compute + store B ----
#pragma unroll 2
    for (int i = 0; i < JJ; ++i) {
        const float* __restrict__ mrow = Msl + i * JPAD;
        f2 acc = {0.0f, 0.0f};
#pragma unroll
        for (int j = 0; j < JJ; ++j) {
            const float m = mrow[j];          // uniform -> scalar load
            acc.x = fmaf(m, xvB[j].x, acc.x);
            acc.y = fmaf(m, xvB[j].y, acc.y);
        }
        __builtin_nontemporal_store(acc, ooutB + i * 128);
    }
}

extern "C" void kernel_launch(void* const* d_in, const int* in_sizes, int n_in,
                              void* d_out, int out_size, void* d_ws, size_t ws_size,
                              hipStream_t stream) {
    const float* x    = (const float*)d_in[0];   // [B,L,J,C]
    const float* A    = (const float*)d_in[1];   // [J,J]
    const float* kern = (const float*)d_in[2];   // [F,K,L]
    float* out        = (float*)d_out;           // [L,B,J,C]
    float* Mg         = (float*)d_ws;            // [LL][JJ][JPAD] = 56 KB

    GCN_precompute_M<<<LL, 256, 0, stream>>>(A, kern, Mg);

    const int grid = LL * (BB / 4);  // 10240 blocks
    GCNLayer_72602127172024_kernel<<<grid, 256, 0, stream>>>(x, Mg, out);
}

// Round 9
// 401.017 us; speedup vs baseline: 1.3230x; 1.0169x over previous
//
#include <hip/hip_runtime.h>

// Problem constants (fixed by reference setup_inputs)
#define BB   2048   // batch
#define LL   20     // seq length
#define JJ   25     // joints
#define CC   256    // channels
#define FF   64     // filters
#define KK   4      // hops
#define JPAD 28     // padded row length (rows 16B-aligned for s_load_dwordx4)
#define MSZ  (JJ * JPAD)   // 700 floats per l-slice of M

typedef float f4 __attribute__((ext_vector_type(4)));

// ---------------------------------------------------------------------------
// Kernel 1 (tiny): M[l,i,j] = sum_k w[k,l]*A[i,j]^k, w[k,l]=sum_n kern[n,k,l]
// One block per l; writes [LL][JJ][JPAD] floats (pad zeroed) into d_ws.
// ---------------------------------------------------------------------------
__global__ __launch_bounds__(256) void GCN_precompute_M(
    const float* __restrict__ A,     // [J,J]
    const float* __restrict__ kern,  // [F,K,L]
    float* __restrict__ Mg)          // [LL][JJ][JPAD]
{
    const int l = blockIdx.x;
    __shared__ float w_sh[KK];

    {
        const int k    = threadIdx.x >> 6;   // wave id == hop (KK==4 waves)
        const int lane = threadIdx.x & 63;   // filter index (FF==64 exactly)
        float v = kern[lane * (KK * LL) + k * LL + l];
        v += __shfl_xor(v, 32, 64);
        v += __shfl_xor(v, 16, 64);
        v += __shfl_xor(v, 8, 64);
        v += __shfl_xor(v, 4, 64);
        v += __shfl_xor(v, 2, 64);
        v += __shfl_xor(v, 1, 64);
        if (lane == 0) w_sh[k] = v;
    }
    __syncthreads();

    const float w0 = w_sh[0], w1 = w_sh[1], w2 = w_sh[2], w3 = w_sh[3];

    for (int e = threadIdx.x; e < MSZ; e += 256) {
        const int i = e / JPAD;
        const int j = e - i * JPAD;
        float m = 0.0f;
        if (j < JJ) {
            const float a = A[i * JJ + j];
            m = w0 + a * (w1 + a * (w2 + a * w3));   // Horner; a=0 -> w0 (0^0==1)
        }
        Mg[l * MSZ + e] = m;
    }
}

// ---------------------------------------------------------------------------
// Kernel 2 (hot): r6 skeleton at FLOAT4 granularity (16B/lane = 1KB/wave
// transactions on both streams, matching the 6.29 TB/s copy ubench).
// Up-front 25-deep nt load burst (xv = 100 VGPR, fits 128 -> 4 waves/SIMD);
// M rows via the scalar pipe (uniform s_load, K$-hot): no LDS, no barriers.
// Grid: LL*(BB/4); block = 256 threads = 4 batch-subs x 64 f4 cols.
// ---------------------------------------------------------------------------
__global__ __launch_bounds__(256, 4) void GCNLayer_72602127172024_kernel(
    const float* __restrict__ x,     // [B,L,J,C]
    const float* __restrict__ Mg,    // [LL][JJ][JPAD]
    float* __restrict__ out)         // [L,B,J,C]
{
    const int tid = threadIdx.x;
    const int gid = blockIdx.x;
    const int l   = gid >> 9;           // / (BB/4) == /512
    const int bb  = (gid & 511) << 2;   // base batch of this block

    const int bsub = tid >> 6;        // 0..3
    const int c4   = tid & 63;        // f4 column (CC/4 == 64)
    const int b    = bb + bsub;

    const f4* __restrict__ xin =
        reinterpret_cast<const f4*>(x) + ((b * LL + l) * JJ) * 64 + c4;
    f4* __restrict__ oout =
        reinterpret_cast<f4*>(out) + ((l * BB + b) * JJ) * 64 + c4;

    // Up-front burst: 25 independent nt f4 loads (1KB/wave each).
    f4 xv[JJ];
#pragma unroll
    for (int j = 0; j < JJ; ++j)
        xv[j] = __builtin_nontemporal_load(xin + j * 64);

    // Uniform M base for this block's l (SGPR address).
    const float* __restrict__ Msl = Mg + l * MSZ;

    // Per output joint i: 25 scalar-pipe M values + 100 v_fma, 1KB store.
#pragma unroll 2
    for (int i = 0; i < JJ; ++i) {
        const float* __restrict__ mrow = Msl + i * JPAD;
        f4 acc = {0.0f, 0.0f, 0.0f, 0.0f};
#pragma unroll
        for (int j = 0; j < JJ; ++j) {
            const float m = mrow[j];          // uniform -> scalar load
            acc.x = fmaf(m, xv[j].x, acc.x);
            acc.y = fmaf(m, xv[j].y, acc.y);
            acc.z = fmaf(m, xv[j].z, acc.z);
            acc.w = fmaf(m, xv[j].w, acc.w);
        }
        __builtin_nontemporal_store(acc, oout + i * 64);
    }
}

extern "C" void kernel_launch(void* const* d_in, const int* in_sizes, int n_in,
                              void* d_out, int out_size, void* d_ws, size_t ws_size,
                              hipStream_t stream) {
    const float* x    = (const float*)d_in[0];   // [B,L,J,C]
    const float* A    = (const float*)d_in[1];   // [J,J]
    const float* kern = (const float*)d_in[2];   // [F,K,L]
    float* out        = (float*)d_out;           // [L,B,J,C]
    float* Mg         = (float*)d_ws;            // [LL][JJ][JPAD] = 56 KB

    GCN_precompute_M<<<LL, 256, 0, stream>>>(A, kern, Mg);

    const int grid = LL * (BB / 4);  // 10240 blocks
    GCNLayer_72602127172024_kernel<<<grid, 256, 0, stream>>>(x, Mg, out);
}

// Round 10
// 384.268 us; speedup vs baseline: 1.3807x; 1.0436x over previous
//
#include <hip/hip_runtime.h>

// Problem constants (fixed by reference setup_inputs)
#define BB   2048   // batch
#define LL   20     // seq length
#define JJ   25     // joints
#define CC   256    // channels
#define FF   64     // filters
#define KK   4      // hops
#define JPAD 28     // padded row length for aligned float4 reads of M rows

typedef float f2 __attribute__((ext_vector_type(2)));
typedef float f4 __attribute__((ext_vector_type(4)));

// out[l,b,i,c] = sum_j M[l,i,j] * x[b,l,j,c]
// M[l,i,j]     = sum_k w[k,l] * A[i,j]^k   (elementwise power, Horner)
// w[k,l]       = sum_n kernel[n,k,l]
//
// Measured-best structure (R2, 383.6 us = 5.47 TB/s, 87% of the 6.29 TB/s
// float4-copy ceiling). Grid: LL*(BB/2) blocks; block = 256 threads =
// 2 batch-subs x 128 float2 cols. Per-block: cheap w-reduce + Horner M in
// LDS, then one straight-line slab: 25-deep nt f2 load burst, 25 outputs
// via uniform LDS-broadcast M rows, nt stores.
//
// Variants benchmarked and rejected (all 388-530 us): M precomputed in a
// separate kernel (R4), load-first issue order + 6 waves/SIMD (R5),
// scalar-pipe M with zero LDS (R6), acc-hold streamed-x (R7, latency-
// chained), dual-slab 50-load burst (R8), float4 granularity (R9),
// persistent blocks (R3, VGPR spill disaster).
__global__ __launch_bounds__(256, 4) void GCNLayer_72602127172024_kernel(
    const float* __restrict__ x,     // [B,L,J,C]
    const float* __restrict__ A,     // [J,J]
    const float* __restrict__ kern,  // [F,K,L]
    float* __restrict__ out)         // [L,B,J,C]
{
    __shared__ float w_sh[KK];
    __shared__ __align__(16) float Ms[JJ * JPAD];  // Ms[i*JPAD+j], pad zeroed

    const int tid = threadIdx.x;
    const int gid = blockIdx.x;
    const int l   = gid >> 10;          // / (BB/2) == /1024
    const int bb  = (gid & 1023) << 1;  // base batch of this block

    // ---- w[k] = sum_n kern[n*K*L + k*L + l]; wave k handles hop k, lane = n ----
    {
        const int k    = tid >> 6;   // wave id == hop (KK==4 waves exactly)
        const int lane = tid & 63;   // filter index (FF==64 exactly)
        float v = kern[lane * (KK * LL) + k * LL + l];
        v += __shfl_xor(v, 32, 64);
        v += __shfl_xor(v, 16, 64);
        v += __shfl_xor(v, 8, 64);
        v += __shfl_xor(v, 4, 64);
        v += __shfl_xor(v, 2, 64);
        v += __shfl_xor(v, 1, 64);
        if (lane == 0) w_sh[k] = v;
    }
    __syncthreads();

    const float w0 = w_sh[0], w1 = w_sh[1], w2 = w_sh[2], w3 = w_sh[3];

    // ---- build Ms[i][j] (row-major, padded); pad entries set to 0 ----
    for (int e = tid; e < JJ * JPAD; e += 256) {
        const int i = e / JPAD;
        const int j = e - i * JPAD;
        float m = 0.0f;
        if (j < JJ) {
            const float a = A[i * JJ + j];
            m = w0 + a * (w1 + a * (w2 + a * w3));   // Horner; a=0 -> w0 (0^0==1)
        }
        Ms[e] = m;
    }
    __syncthreads();

    // ---- main: each thread owns one float2 column of one (b,l) slab ----
    const int bsub = tid >> 7;        // 0..1
    const int c2   = tid & 127;       // float2 column (CC/2 == 128)
    const int b    = bb + bsub;

    const f2* __restrict__ xin =
        reinterpret_cast<const f2*>(x) + ((b * LL + l) * JJ) * 128 + c2;
    f2* __restrict__ oout =
        reinterpret_cast<f2*>(out) + ((l * BB + b) * JJ) * 128 + c2;

    // Load the full [J] column slab into registers (25 x float2 = 50 VGPR),
    // coalesced (wave reads 512B per instruction). Nontemporal: pure stream,
    // no reuse -> don't allocate in L2.
    f2 xv[JJ];
#pragma unroll
    for (int j = 0; j < JJ; ++j) xv[j] = __builtin_nontemporal_load(xin + j * 128);

    // For each output joint i: read M row i as 7 float4 LDS broadcasts
    // (uniform address -> conflict-free), accumulate, store immediately.
#pragma unroll
    for (int i = 0; i < JJ; ++i) {
        const f4* mrow = reinterpret_cast<const f4*>(Ms + i * JPAD);
        f2 acc = {0.0f, 0.0f};
#pragma unroll
        for (int j4 = 0; j4 < 7; ++j4) {
            const f4 m4 = mrow[j4];
#pragma unroll
            for (int comp = 0; comp < 4; ++comp) {
                const int j = j4 * 4 + comp;
                if (j < JJ) {   // compile-time pruned (full unroll)
                    const float m = m4[comp];
                    acc.x = fmaf(m, xv[j].x, acc.x);
                    acc.y = fmaf(m, xv[j].y, acc.y);
                }
            }
        }
        __builtin_nontemporal_store(acc, oout + i * 128);
    }
}

extern "C" void kernel_launch(void* const* d_in, const int* in_sizes, int n_in,
                              void* d_out, int out_size, void* d_ws, size_t ws_size,
                              hipStream_t stream) {
    const float* x    = (const float*)d_in[0];   // [B,L,J,C]
    const float* A    = (const float*)d_in[1];   // [J,J]
    const float* kern = (const float*)d_in[2];   // [F,K,L]
    float* out        = (float*)d_out;           // [L,B,J,C]

    const int grid = LL * (BB / 2);  // 20480 blocks
    GCNLayer_72602127172024_kernel<<<grid, 256, 0, stream>>>(x, A, kern, out);
}